// Round 2
// baseline (267.162 us; speedup 1.0000x reference)
//
#include <hip/hip_runtime.h>

// LightningIndexer: out[b,q,k] = sum_h w_h * relu( (xWq^T+bq)[b,q,h,:] . (xWk^T+bk)[b,k,h,:] )
// B=2, S=4096, Dmodel=1024, H=4, HD=64.
// R2: LDS-free design. MFMA fragments (lane = 8 contiguous k at row lane&15)
// are loaded directly from global via dwordx4 (64B segments per 16-lane row
// group, L2/LLC-served). No barriers, no vmcnt(0) drains -> compiler pipelines
// loads across iterations; occupancy limited only by VGPRs.

typedef __bf16 bf16;
typedef __bf16 bf16x4 __attribute__((ext_vector_type(4)));
typedef __bf16 bf16x8 __attribute__((ext_vector_type(8)));
typedef float f32x4 __attribute__((ext_vector_type(4)));

#define NB 2
#define SEQ 4096
#define DMODEL 1024
#define NHEAD 4
#define HDIM 64
#define NPROJ 256       // NHEAD*HDIM
#define MTOT 8192       // NB*SEQ

// ---------------- K0: convert Wq, Wk fp32 -> bf16 ----------------
__global__ __launch_bounds__(256) void k_convert(const float* __restrict__ wq,
                                                 const float* __restrict__ wk,
                                                 bf16* __restrict__ wqb,
                                                 bf16* __restrict__ wkb) {
  int i = blockIdx.x * 256 + threadIdx.x;  // 65536 float4 groups
  float4 a = ((const float4*)wq)[i];
  bf16x4 oa = {(bf16)a.x, (bf16)a.y, (bf16)a.z, (bf16)a.w};
  ((bf16x4*)wqb)[i] = oa;
  float4 b = ((const float4*)wk)[i];
  bf16x4 ob = {(bf16)b.x, (bf16)b.y, (bf16)b.z, (bf16)b.w};
  ((bf16x4*)wkb)[i] = ob;
}

// ---------------- K1: projection GEMM (LDS-free) ----------------
// out[m,n] = sum_k x[m,k]*W[n,k] + bias[n], stored bf16.
// BM=32, BN=256. grid (256, 2): y selects Q/K. 4 waves, each 32x64 cols.
// A frags: direct fp32 dwordx4 x2 + cvt; B frags: direct bf16 dwordx4.
__global__ __launch_bounds__(256, 4) void k_proj(
    const float* __restrict__ x, const bf16* __restrict__ wqb,
    const bf16* __restrict__ wkb, const float* __restrict__ qbias,
    const float* __restrict__ kbias, bf16* __restrict__ Qb,
    bf16* __restrict__ Kb) {
  const int t = threadIdx.x;
  const int lane = t & 63, w = t >> 6;
  const int m16 = lane & 15, q = lane >> 4;
  const int m0 = blockIdx.x * 32;
  const int z = blockIdx.y;
  const bf16* __restrict__ W = z ? wkb : wqb;

  f32x4 acc[2][4];
#pragma unroll
  for (int i = 0; i < 2; i++)
#pragma unroll
    for (int j = 0; j < 4; j++) acc[i][j] = {0.f, 0.f, 0.f, 0.f};

  // per-lane base pointers
  const float* xp = x + (size_t)(m0 + m16) * DMODEL + q * 8;
  const bf16* wp = W + (size_t)(w * 64 + m16) * DMODEL + q * 8;

  for (int kt = 0; kt < 16; kt++) {
    bf16x8 a[2][2];
#pragma unroll
    for (int mt = 0; mt < 2; mt++)
#pragma unroll
      for (int s = 0; s < 2; s++) {
        const float* p = xp + (size_t)mt * 16 * DMODEL + kt * 64 + s * 32;
        float4 v0 = *(const float4*)p;
        float4 v1 = *(const float4*)(p + 4);
        a[mt][s] = bf16x8{(bf16)v0.x, (bf16)v0.y, (bf16)v0.z, (bf16)v0.w,
                          (bf16)v1.x, (bf16)v1.y, (bf16)v1.z, (bf16)v1.w};
      }
    bf16x8 b[4][2];
#pragma unroll
    for (int nt = 0; nt < 4; nt++)
#pragma unroll
      for (int s = 0; s < 2; s++)
        b[nt][s] = *(const bf16x8*)(wp + (size_t)nt * 16 * DMODEL + kt * 64 + s * 32);
#pragma unroll
    for (int mt = 0; mt < 2; mt++)
#pragma unroll
      for (int nt = 0; nt < 4; nt++)
#pragma unroll
        for (int s = 0; s < 2; s++)
          acc[mt][nt] = __builtin_amdgcn_mfma_f32_16x16x32_bf16(
              a[mt][s], b[nt][s], acc[mt][nt], 0, 0, 0);
  }

  const float* __restrict__ bias = z ? kbias : qbias;
  bf16* __restrict__ outp = z ? Kb : Qb;
#pragma unroll
  for (int nt = 0; nt < 4; nt++) {
    int col = w * 64 + nt * 16 + m16;   // C/D: col = lane&15
    float bv = bias[col];
#pragma unroll
    for (int mt = 0; mt < 2; mt++) {
      int row0 = m0 + mt * 16 + q * 4;  // C/D: row = quad*4 + reg
#pragma unroll
      for (int e = 0; e < 4; e++)
        outp[(size_t)(row0 + e) * NPROJ + col] = (bf16)(acc[mt][nt][e] + bv);
    }
  }
}

// ---------------- K2: scores (LDS-free) ----------------
// grid (32 ktiles, 32 qtiles, 2 batches); 256 threads; out tile 128x128.
// Per wave 64x64 quadrant; fragments loaded directly from Qb/Kb (L2-resident);
// per head: 16 tiles x 2-chain K=32 MFMA, fold accf += w_h*relu(S). No LDS.
__global__ __launch_bounds__(256, 3) void k_scores(
    const bf16* __restrict__ Qb, const bf16* __restrict__ Kb,
    const float* __restrict__ iw, float* __restrict__ out) {
  const int t = threadIdx.x;
  const int lane = t & 63, w = t >> 6;
  const int m16 = lane & 15, q = lane >> 4;
  const int kx = blockIdx.x, qy = blockIdx.y, bz = blockIdx.z;
  const int rh = (w >> 1) * 64, ch = (w & 1) * 64;  // wave quadrant

  f32x4 accf[4][4];
#pragma unroll
  for (int i = 0; i < 4; i++)
#pragma unroll
    for (int j = 0; j < 4; j++) accf[i][j] = {0.f, 0.f, 0.f, 0.f};

  const float w0 = iw[0], w1 = iw[1], w2 = iw[2], w3 = iw[3];
  const float whs[4] = {w0, w1, w2, w3};

  // per-lane row pointers (row = tile_base + m16; k-offset q*8)
  const bf16* qp = Qb + (size_t)(bz * SEQ + qy * 128 + rh + m16) * NPROJ + q * 8;
  const bf16* kp = Kb + (size_t)(bz * SEQ + kx * 128 + ch + m16) * NPROJ + q * 8;

  for (int h = 0; h < NHEAD; h++) {
    const int ho = h * 64;
    bf16x8 a0[4], a1[4], b0[4], b1[4];
#pragma unroll
    for (int i = 0; i < 4; i++) {
      const bf16* qpi = qp + (size_t)i * 16 * NPROJ + ho;
      a0[i] = *(const bf16x8*)(qpi);
      a1[i] = *(const bf16x8*)(qpi + 32);
      const bf16* kpi = kp + (size_t)i * 16 * NPROJ + ho;
      b0[i] = *(const bf16x8*)(kpi);
      b1[i] = *(const bf16x8*)(kpi + 32);
    }
    float wh = whs[h];
#pragma unroll
    for (int mt = 0; mt < 4; mt++)
#pragma unroll
      for (int nt = 0; nt < 4; nt++) {
        f32x4 tacc = {0.f, 0.f, 0.f, 0.f};
        tacc = __builtin_amdgcn_mfma_f32_16x16x32_bf16(a0[mt], b0[nt], tacc, 0, 0, 0);
        tacc = __builtin_amdgcn_mfma_f32_16x16x32_bf16(a1[mt], b1[nt], tacc, 0, 0, 0);
#pragma unroll
        for (int e = 0; e < 4; e++)
          accf[mt][nt][e] += wh * fmaxf(tacc[e], 0.f);
      }
  }

#pragma unroll
  for (int mt = 0; mt < 4; mt++)
#pragma unroll
    for (int e = 0; e < 4; e++) {
      int row = qy * 128 + rh + mt * 16 + q * 4 + e;
      size_t ob = ((size_t)bz * SEQ + row) * SEQ + (size_t)kx * 128 + ch;
#pragma unroll
      for (int nt = 0; nt < 4; nt++)
        out[ob + nt * 16 + m16] = accf[mt][nt][e];
    }
}

extern "C" void kernel_launch(void* const* d_in, const int* in_sizes, int n_in,
                              void* d_out, int out_size, void* d_ws, size_t ws_size,
                              hipStream_t stream) {
  const float* x  = (const float*)d_in[0];   // [2,4096,1024]
  const float* wq = (const float*)d_in[1];   // [256,1024]
  const float* qb = (const float*)d_in[2];   // [256]
  const float* wk = (const float*)d_in[3];   // [256,1024]
  const float* kb = (const float*)d_in[4];   // [256]
  const float* iw = (const float*)d_in[5];   // [4]
  float* out = (float*)d_out;                // [2,4096,4096]

  // workspace layout (9,437,184 B total)
  char* ws = (char*)d_ws;
  bf16* wqb = (bf16*)ws;                               // 512 KB
  bf16* wkb = (bf16*)(ws + 524288);                    // 512 KB
  bf16* Qb  = (bf16*)(ws + 1048576);                   // 4 MB  [8192][256]
  bf16* Kb  = (bf16*)(ws + 1048576 + 4194304);         // 4 MB  [8192][256]

  k_convert<<<256, 256, 0, stream>>>(wq, wk, wqb, wkb);
  k_proj<<<dim3(256, 2, 1), 256, 0, stream>>>(x, wqb, wkb, qb, kb, Qb, Kb);
  k_scores<<<dim3(32, 32, 2), 256, 0, stream>>>(Qb, Kb, iw, out);
}

// Round 3
// 202.567 us; speedup vs baseline: 1.3189x; 1.3189x over previous
//
#include <hip/hip_runtime.h>

// LightningIndexer: out[b,q,k] = sum_h w_h * relu( (xWq^T+bq)[b,q,h,:] . (xWk^T+bk)[b,k,h,:] )
// B=2, S=4096, Dmodel=1024, H=4, HD=64.
// R3: back to async16+LDS (R2's LDS-free regressed: scattered fragment loads,
// LLC-bound). Fixes vs R1:
//  - k_scores: XCD-swizzled block mapping (XCD owns 8 (qy,bz) rows x all kx ->
//    K-set 2MB + Q-set 0.5MB L2-resident), 2-heads-per-stage (4 barriers/block,
//    64 MFMA per drain, 64KB LDS, 2 blocks/CU).
//  - k_proj: BN=128 split -> 512 blocks = 2/CU (R1 had 1 block/CU: every kt
//    iteration exposed a full HBM-latency barrier drain).

typedef __bf16 bf16;
typedef __bf16 bf16x4 __attribute__((ext_vector_type(4)));
typedef __bf16 bf16x8 __attribute__((ext_vector_type(8)));
typedef float f32x4 __attribute__((ext_vector_type(4)));

#define NB 2
#define SEQ 4096
#define DMODEL 1024
#define NHEAD 4
#define HDIM 64
#define NPROJ 256       // NHEAD*HDIM
#define MTOT 8192       // NB*SEQ

// async global->LDS, 16B per lane; LDS dest = wave-uniform base + lane*16
__device__ __forceinline__ void async16(const void* g, void* l) {
  __builtin_amdgcn_global_load_lds(
      (const __attribute__((address_space(1))) void*)g,
      (__attribute__((address_space(3))) void*)l, 16, 0, 0);
}

// ---------------- K0: convert Wq, Wk fp32 -> bf16 ----------------
__global__ __launch_bounds__(256) void k_convert(const float* __restrict__ wq,
                                                 const float* __restrict__ wk,
                                                 bf16* __restrict__ wqb,
                                                 bf16* __restrict__ wkb) {
  int i = blockIdx.x * 256 + threadIdx.x;  // 65536 float4 groups
  float4 a = ((const float4*)wq)[i];
  bf16x4 oa = {(bf16)a.x, (bf16)a.y, (bf16)a.z, (bf16)a.w};
  ((bf16x4*)wqb)[i] = oa;
  float4 b = ((const float4*)wk)[i];
  bf16x4 ob = {(bf16)b.x, (bf16)b.y, (bf16)b.z, (bf16)b.w};
  ((bf16x4*)wkb)[i] = ob;
}

// ---------------- K1: projection GEMM ----------------
// out[m,n] = sum_k x[m,k]*W[n,k] + bias[n], stored bf16.
// BM=64, BN=128, BK=64. grid (128 mtiles, 2 z, 2 nhalf) = 512 blocks, 2/CU.
// 4 waves; wave w owns cols w*32 (2 n-tiles) x 64 rows (4 m-tiles).
__global__ __launch_bounds__(256, 4) void k_proj(
    const float* __restrict__ x, const bf16* __restrict__ wqb,
    const bf16* __restrict__ wkb, const float* __restrict__ qbias,
    const float* __restrict__ kbias, bf16* __restrict__ Qb,
    bf16* __restrict__ Kb) {
  __shared__ __align__(16) bf16 As[64 * 72];   // padded rows
  __shared__ __align__(16) bf16 Bs[128 * 64];  // async16, XOR chunk swizzle
  const int t = threadIdx.x;
  const int lane = t & 63, w = t >> 6;
  const int m16 = lane & 15, q = lane >> 4;
  const int m0 = blockIdx.x * 64;
  const int z = blockIdx.y;
  const int nh = blockIdx.z;                   // n half: cols nh*128..+127
  const bf16* __restrict__ W = z ? wkb : wqb;

  f32x4 acc[4][2];
#pragma unroll
  for (int i = 0; i < 4; i++)
#pragma unroll
    for (int j = 0; j < 2; j++) acc[i][j] = {0.f, 0.f, 0.f, 0.f};

  for (int kt = 0; kt < 16; kt++) {
    // async stage W slab [128 rows][64 bf16], 8 rows per call, 4 calls/wave
#pragma unroll
    for (int p = 0; p < 4; p++) {
      int n0 = w * 32 + p * 8;                 // wave-uniform base
      int r = n0 + (lane >> 3);
      int c = (lane & 7) ^ (r & 7);            // swizzled source chunk
      async16(W + (size_t)(nh * 128 + r) * DMODEL + kt * 64 + c * 8,
              Bs + n0 * 64);
    }
    // stage x tile [64][64] fp32 -> bf16 via registers
#pragma unroll
    for (int p = 0; p < 4; p++) {
      int r = p * 16 + (t >> 4);
      int c = (t & 15) * 4;
      float4 v = *(const float4*)(x + (size_t)(m0 + r) * DMODEL + kt * 64 + c);
      bf16x4 o = {(bf16)v.x, (bf16)v.y, (bf16)v.z, (bf16)v.w};
      *(bf16x4*)(As + r * 72 + c) = o;
    }
    __builtin_amdgcn_s_waitcnt(0);
    __syncthreads();

#pragma unroll
    for (int s = 0; s < 2; s++) {
      bf16x8 a[4], b[2];
#pragma unroll
      for (int mt = 0; mt < 4; mt++)
        a[mt] = *(const bf16x8*)(As + (mt * 16 + m16) * 72 + s * 32 + q * 8);
#pragma unroll
      for (int nt = 0; nt < 2; nt++) {
        int n = w * 32 + nt * 16 + m16;
        int cc = (4 * s + q) ^ (n & 7);
        b[nt] = *(const bf16x8*)(Bs + n * 64 + cc * 8);
      }
#pragma unroll
      for (int mt = 0; mt < 4; mt++)
#pragma unroll
        for (int nt = 0; nt < 2; nt++)
          acc[mt][nt] = __builtin_amdgcn_mfma_f32_16x16x32_bf16(
              a[mt], b[nt], acc[mt][nt], 0, 0, 0);
    }
    __syncthreads();
  }

  const float* __restrict__ bias = z ? kbias : qbias;
  bf16* __restrict__ outp = z ? Kb : Qb;
#pragma unroll
  for (int nt = 0; nt < 2; nt++) {
    int col = nh * 128 + w * 32 + nt * 16 + m16;  // C/D: col = lane&15
    float bv = bias[col];
#pragma unroll
    for (int mt = 0; mt < 4; mt++) {
      int row0 = m0 + mt * 16 + q * 4;            // C/D: row = quad*4 + reg
#pragma unroll
      for (int e = 0; e < 4; e++)
        outp[(size_t)(row0 + e) * NPROJ + col] = (bf16)(acc[mt][nt][e] + bv);
    }
  }
}

// ---------------- K2: scores ----------------
// 2048 blocks flat, XCD-swizzled: L%8 = xcd owns rows xcd*8..+7 (row=(bz,qy)),
// slot walks kx fastest -> per-XCD working set: K 2MB + Q 0.5MB (L2-resident).
// Per block: out tile 128x128; 2 stage rounds of 2 heads each (Qs/Ks 32KB ea).
// LDS layout (forced by wave-uniform async16 dest): [rowgroup(8 rows)][head
// half][8 chunks of 16B], XOR chunk swizzle (uniform bank load for b128 reads).
__global__ __launch_bounds__(256, 2) void k_scores(
    const bf16* __restrict__ Qb, const bf16* __restrict__ Kb,
    const float* __restrict__ iw, float* __restrict__ out) {
  __shared__ __align__(16) bf16 Qs[16 * 2 * 512];  // 32 KB
  __shared__ __align__(16) bf16 Ks[16 * 2 * 512];  // 32 KB
  const int t = threadIdx.x;
  const int lane = t & 63, w = t >> 6;
  const int m16 = lane & 15, q = lane >> 4;

  // XCD swizzle: blockIdx.x -> (bz, qy, kx)
  const int L = blockIdx.x;            // 0..2047
  const int xcd = L & 7;
  const int slot = L >> 3;             // 0..255
  const int row = xcd * 8 + (slot >> 5);  // 0..63
  const int kx = slot & 31;
  const int bz = row >> 5;
  const int qy = row & 31;

  const int rh = (w >> 1) * 64, ch = (w & 1) * 64;  // wave quadrant

  f32x4 accf[4][4];
#pragma unroll
  for (int i = 0; i < 4; i++)
#pragma unroll
    for (int j = 0; j < 4; j++) accf[i][j] = {0.f, 0.f, 0.f, 0.f};

  const size_t qbase = ((size_t)bz * SEQ + (size_t)qy * 128) * NPROJ;
  const size_t kbase = ((size_t)bz * SEQ + (size_t)kx * 128) * NPROJ;

  for (int hp = 0; hp < 2; hp++) {
    // stage heads 2*hp, 2*hp+1: 32 calls per array, 8 per wave
#pragma unroll
    for (int p = 0; p < 8; p++) {
      int idx = w * 8 + p;             // rowgroup*2 + headhalf, wave-uniform
      int g = idx >> 1, hh = idx & 1;
      int r = g * 8 + (lane >> 3);
      int c = (lane & 7) ^ (r & 7);    // XOR chunk swizzle
      size_t src = (size_t)r * NPROJ + (hp * 2 + hh) * 64 + c * 8;
      async16(Qb + qbase + src, Qs + idx * 512);
      async16(Kb + kbase + src, Ks + idx * 512);
    }
    __builtin_amdgcn_s_waitcnt(0);
    __syncthreads();

#pragma unroll
    for (int hh = 0; hh < 2; hh++) {
      float wh = iw[hp * 2 + hh];
      bf16x8 b0[4], b1[4];
#pragma unroll
      for (int nt = 0; nt < 4; nt++) {
        int n = ch + nt * 16 + m16;
        const bf16* kb_ = Ks + (n >> 3) * 1024 + hh * 512 + (n & 7) * 64;
        b0[nt] = *(const bf16x8*)(kb_ + ((q) ^ (n & 7)) * 8);
        b1[nt] = *(const bf16x8*)(kb_ + ((4 + q) ^ (n & 7)) * 8);
      }
#pragma unroll
      for (int mt = 0; mt < 4; mt++) {
        int m = rh + mt * 16 + m16;
        const bf16* qa = Qs + (m >> 3) * 1024 + hh * 512 + (m & 7) * 64;
        bf16x8 a0 = *(const bf16x8*)(qa + ((q) ^ (m & 7)) * 8);
        bf16x8 a1 = *(const bf16x8*)(qa + ((4 + q) ^ (m & 7)) * 8);
#pragma unroll
        for (int nt = 0; nt < 4; nt++) {
          f32x4 tacc = {0.f, 0.f, 0.f, 0.f};
          tacc = __builtin_amdgcn_mfma_f32_16x16x32_bf16(a0, b0[nt], tacc, 0, 0, 0);
          tacc = __builtin_amdgcn_mfma_f32_16x16x32_bf16(a1, b1[nt], tacc, 0, 0, 0);
#pragma unroll
          for (int e = 0; e < 4; e++)
            accf[mt][nt][e] += wh * fmaxf(tacc[e], 0.f);
        }
      }
    }
    __syncthreads();
  }

#pragma unroll
  for (int mt = 0; mt < 4; mt++)
#pragma unroll
    for (int e = 0; e < 4; e++) {
      int r = qy * 128 + rh + mt * 16 + q * 4 + e;
      size_t ob = ((size_t)bz * SEQ + r) * SEQ + (size_t)kx * 128 + ch;
#pragma unroll
      for (int nt = 0; nt < 4; nt++)
        out[ob + nt * 16 + m16] = accf[mt][nt][e];
    }
}

extern "C" void kernel_launch(void* const* d_in, const int* in_sizes, int n_in,
                              void* d_out, int out_size, void* d_ws, size_t ws_size,
                              hipStream_t stream) {
  const float* x  = (const float*)d_in[0];   // [2,4096,1024]
  const float* wq = (const float*)d_in[1];   // [256,1024]
  const float* qb = (const float*)d_in[2];   // [256]
  const float* wk = (const float*)d_in[3];   // [256,1024]
  const float* kb = (const float*)d_in[4];   // [256]
  const float* iw = (const float*)d_in[5];   // [4]
  float* out = (float*)d_out;                // [2,4096,4096]

  // workspace layout (9,437,184 B total)
  char* ws = (char*)d_ws;
  bf16* wqb = (bf16*)ws;                               // 512 KB
  bf16* wkb = (bf16*)(ws + 524288);                    // 512 KB
  bf16* Qb  = (bf16*)(ws + 1048576);                   // 4 MB  [8192][256]
  bf16* Kb  = (bf16*)(ws + 1048576 + 4194304);         // 4 MB  [8192][256]

  k_convert<<<256, 256, 0, stream>>>(wq, wk, wqb, wkb);
  k_proj<<<dim3(128, 2, 2), 256, 0, stream>>>(x, wqb, wkb, qb, kb, Qb, Kb);
  k_scores<<<2048, 256, 0, stream>>>(Qb, Kb, iw, out);
}

// Round 4
// 195.815 us; speedup vs baseline: 1.3644x; 1.0345x over previous
//
#include <hip/hip_runtime.h>

// LightningIndexer: out[b,q,k] = sum_h w_h * relu( (xWq^T+bq)[b,q,h,:] . (xWk^T+bk)[b,k,h,:] )
// B=2, S=4096, Dmodel=1024, H=4, HD=64.
// R4: k_scores restructured: Q strip (128 rows, all heads) in REGISTERS
// (loaded once per block), loop over 4 K-tiles; per tile stage K 64KB (all
// heads) via swizzled async16, 128 MFMA per wave per barrier-drain, stores
// inside the loop. Staging traffic halved (134MB), A-side LDS reads gone.
// k_proj/k_convert unchanged from R3.

typedef __bf16 bf16;
typedef __bf16 bf16x4 __attribute__((ext_vector_type(4)));
typedef __bf16 bf16x8 __attribute__((ext_vector_type(8)));
typedef float f32x4 __attribute__((ext_vector_type(4)));

#define NB 2
#define SEQ 4096
#define DMODEL 1024
#define NHEAD 4
#define HDIM 64
#define NPROJ 256       // NHEAD*HDIM
#define MTOT 8192       // NB*SEQ

// async global->LDS, 16B per lane; LDS dest = wave-uniform base + lane*16
__device__ __forceinline__ void async16(const void* g, void* l) {
  __builtin_amdgcn_global_load_lds(
      (const __attribute__((address_space(1))) void*)g,
      (__attribute__((address_space(3))) void*)l, 16, 0, 0);
}

// ---------------- K0: convert Wq, Wk fp32 -> bf16 ----------------
__global__ __launch_bounds__(256) void k_convert(const float* __restrict__ wq,
                                                 const float* __restrict__ wk,
                                                 bf16* __restrict__ wqb,
                                                 bf16* __restrict__ wkb) {
  int i = blockIdx.x * 256 + threadIdx.x;  // 65536 float4 groups
  float4 a = ((const float4*)wq)[i];
  bf16x4 oa = {(bf16)a.x, (bf16)a.y, (bf16)a.z, (bf16)a.w};
  ((bf16x4*)wqb)[i] = oa;
  float4 b = ((const float4*)wk)[i];
  bf16x4 ob = {(bf16)b.x, (bf16)b.y, (bf16)b.z, (bf16)b.w};
  ((bf16x4*)wkb)[i] = ob;
}

// ---------------- K1: projection GEMM ----------------
// out[m,n] = sum_k x[m,k]*W[n,k] + bias[n], stored bf16.
// BM=64, BN=128, BK=64. grid (128 mtiles, 2 z, 2 nhalf) = 512 blocks, 2/CU.
__global__ __launch_bounds__(256, 4) void k_proj(
    const float* __restrict__ x, const bf16* __restrict__ wqb,
    const bf16* __restrict__ wkb, const float* __restrict__ qbias,
    const float* __restrict__ kbias, bf16* __restrict__ Qb,
    bf16* __restrict__ Kb) {
  __shared__ __align__(16) bf16 As[64 * 72];   // padded rows
  __shared__ __align__(16) bf16 Bs[128 * 64];  // async16, XOR chunk swizzle
  const int t = threadIdx.x;
  const int lane = t & 63, w = t >> 6;
  const int m16 = lane & 15, q = lane >> 4;
  const int m0 = blockIdx.x * 64;
  const int z = blockIdx.y;
  const int nh = blockIdx.z;                   // n half: cols nh*128..+127
  const bf16* __restrict__ W = z ? wkb : wqb;

  f32x4 acc[4][2];
#pragma unroll
  for (int i = 0; i < 4; i++)
#pragma unroll
    for (int j = 0; j < 2; j++) acc[i][j] = {0.f, 0.f, 0.f, 0.f};

  for (int kt = 0; kt < 16; kt++) {
#pragma unroll
    for (int p = 0; p < 4; p++) {
      int n0 = w * 32 + p * 8;                 // wave-uniform base
      int r = n0 + (lane >> 3);
      int c = (lane & 7) ^ (r & 7);            // swizzled source chunk
      async16(W + (size_t)(nh * 128 + r) * DMODEL + kt * 64 + c * 8,
              Bs + n0 * 64);
    }
#pragma unroll
    for (int p = 0; p < 4; p++) {
      int r = p * 16 + (t >> 4);
      int c = (t & 15) * 4;
      float4 v = *(const float4*)(x + (size_t)(m0 + r) * DMODEL + kt * 64 + c);
      bf16x4 o = {(bf16)v.x, (bf16)v.y, (bf16)v.z, (bf16)v.w};
      *(bf16x4*)(As + r * 72 + c) = o;
    }
    __builtin_amdgcn_s_waitcnt(0);
    __syncthreads();

#pragma unroll
    for (int s = 0; s < 2; s++) {
      bf16x8 a[4], b[2];
#pragma unroll
      for (int mt = 0; mt < 4; mt++)
        a[mt] = *(const bf16x8*)(As + (mt * 16 + m16) * 72 + s * 32 + q * 8);
#pragma unroll
      for (int nt = 0; nt < 2; nt++) {
        int n = w * 32 + nt * 16 + m16;
        int cc = (4 * s + q) ^ (n & 7);
        b[nt] = *(const bf16x8*)(Bs + n * 64 + cc * 8);
      }
#pragma unroll
      for (int mt = 0; mt < 4; mt++)
#pragma unroll
        for (int nt = 0; nt < 2; nt++)
          acc[mt][nt] = __builtin_amdgcn_mfma_f32_16x16x32_bf16(
              a[mt], b[nt], acc[mt][nt], 0, 0, 0);
    }
    __syncthreads();
  }

  const float* __restrict__ bias = z ? kbias : qbias;
  bf16* __restrict__ outp = z ? Kb : Qb;
#pragma unroll
  for (int nt = 0; nt < 2; nt++) {
    int col = nh * 128 + w * 32 + nt * 16 + m16;  // C/D: col = lane&15
    float bv = bias[col];
#pragma unroll
    for (int mt = 0; mt < 4; mt++) {
      int row0 = m0 + mt * 16 + q * 4;            // C/D: row = quad*4 + reg
#pragma unroll
      for (int e = 0; e < 4; e++)
        outp[(size_t)(row0 + e) * NPROJ + col] = (bf16)(acc[mt][nt][e] + bv);
    }
  }
}

// ---------------- K2: scores ----------------
// grid 512 blocks (= 2/CU exactly). Block: Q strip of 128 rows (bz, q0) held
// in registers (all 4 heads); loops 4 K-tiles (kq*4+i). Per tile: stage
// K[128 rows][256 cols] = 64KB LDS (XOR chunk swizzle, 2 rows per async16
// call), then per wave: 4 heads x 2 mt x 8 nt x 2-chain MFMA (128 MFMA per
// drain), fold w_h*relu, store 32x128 chunk. LDS row = 512B; b-frag slot
// = (h*8+j*4+q) ^ (n&31) -> banks covered 2x (free).
__global__ __launch_bounds__(256, 2) void k_scores(
    const bf16* __restrict__ Qb, const bf16* __restrict__ Kb,
    const float* __restrict__ iw, float* __restrict__ out) {
  __shared__ __align__(16) bf16 Ks[128 * 256];  // 64 KB
  const int t = threadIdx.x;
  const int lane = t & 63, w = t >> 6;
  const int m16 = lane & 15, q = lane >> 4;

  const int bx = blockIdx.x;
  const int kq = bx & 7;          // K-tile group: tiles kq*4 .. kq*4+3
  const int strip = bx >> 3;      // 0..63
  const int bz = strip >> 5;
  const int q0 = (strip & 31) * 128;

  const float wh0 = iw[0], wh1 = iw[1], wh2 = iw[2], wh3 = iw[3];
  const float whs[4] = {wh0, wh1, wh2, wh3};

  // ---- load Q strip fragments to registers (once) ----
  // wave w owns rows q0 + w*32 + mt*16 + m16; k = h*64 + j*32 + q*8
  bf16x8 aq[2][4][2];
  {
    const bf16* qp =
        Qb + (size_t)(bz * SEQ + q0 + w * 32 + m16) * NPROJ + q * 8;
#pragma unroll
    for (int mt = 0; mt < 2; mt++)
#pragma unroll
      for (int h = 0; h < 4; h++)
#pragma unroll
        for (int j = 0; j < 2; j++)
          aq[mt][h][j] =
              *(const bf16x8*)(qp + (size_t)mt * 16 * NPROJ + h * 64 + j * 32);
  }

  for (int i = 0; i < 4; i++) {
    const int kx = kq * 4 + i;
    const size_t kbase = ((size_t)bz * SEQ + (size_t)kx * 128) * NPROJ;
    __syncthreads();  // prev-iter LDS reads complete before overwrite
    // stage K tile: 64 calls (16/wave), each stages 2 rows (1 KB)
#pragma unroll
    for (int p = 0; p < 16; p++) {
      int g = w * 16 + p;                 // 2-row group, wave-uniform
      int r = g * 2 + (lane >> 5);
      int c = (lane & 31) ^ (r & 31);     // XOR chunk swizzle
      async16(Kb + kbase + (size_t)r * NPROJ + c * 8, Ks + g * 512);
    }
    __builtin_amdgcn_s_waitcnt(0);
    __syncthreads();

    f32x4 accf[2][8];
#pragma unroll
    for (int mt = 0; mt < 2; mt++)
#pragma unroll
      for (int nt = 0; nt < 8; nt++) accf[mt][nt] = {0.f, 0.f, 0.f, 0.f};

#pragma unroll
    for (int h = 0; h < 4; h++) {
      const float wh = whs[h];
      bf16x8 bk[8][2];
#pragma unroll
      for (int nt = 0; nt < 8; nt++) {
        int n = nt * 16 + m16;
        const bf16* kb_ = Ks + (size_t)n * 256;
        int c0 = (h * 8 + q) ^ (n & 31);
        int c1 = (h * 8 + 4 + q) ^ (n & 31);
        bk[nt][0] = *(const bf16x8*)(kb_ + c0 * 8);
        bk[nt][1] = *(const bf16x8*)(kb_ + c1 * 8);
      }
#pragma unroll
      for (int mt = 0; mt < 2; mt++)
#pragma unroll
        for (int nt = 0; nt < 8; nt++) {
          f32x4 tacc = {0.f, 0.f, 0.f, 0.f};
          tacc = __builtin_amdgcn_mfma_f32_16x16x32_bf16(aq[mt][h][0], bk[nt][0],
                                                         tacc, 0, 0, 0);
          tacc = __builtin_amdgcn_mfma_f32_16x16x32_bf16(aq[mt][h][1], bk[nt][1],
                                                         tacc, 0, 0, 0);
#pragma unroll
          for (int e = 0; e < 4; e++)
            accf[mt][nt][e] += wh * fmaxf(tacc[e], 0.f);
        }
    }

    // store 32x128 chunk per wave (rows w*32.., cols kx*128..)
#pragma unroll
    for (int mt = 0; mt < 2; mt++)
#pragma unroll
      for (int e = 0; e < 4; e++) {
        int r = q0 + w * 32 + mt * 16 + q * 4 + e;
        size_t ob = ((size_t)bz * SEQ + r) * SEQ + (size_t)kx * 128;
#pragma unroll
        for (int nt = 0; nt < 8; nt++)
          out[ob + nt * 16 + m16] = accf[mt][nt][e];
      }
  }
}

extern "C" void kernel_launch(void* const* d_in, const int* in_sizes, int n_in,
                              void* d_out, int out_size, void* d_ws, size_t ws_size,
                              hipStream_t stream) {
  const float* x  = (const float*)d_in[0];   // [2,4096,1024]
  const float* wq = (const float*)d_in[1];   // [256,1024]
  const float* qb = (const float*)d_in[2];   // [256]
  const float* wk = (const float*)d_in[3];   // [256,1024]
  const float* kb = (const float*)d_in[4];   // [256]
  const float* iw = (const float*)d_in[5];   // [4]
  float* out = (float*)d_out;                // [2,4096,4096]

  // workspace layout (9,437,184 B total)
  char* ws = (char*)d_ws;
  bf16* wqb = (bf16*)ws;                               // 512 KB
  bf16* wkb = (bf16*)(ws + 524288);                    // 512 KB
  bf16* Qb  = (bf16*)(ws + 1048576);                   // 4 MB  [8192][256]
  bf16* Kb  = (bf16*)(ws + 1048576 + 4194304);         // 4 MB  [8192][256]

  k_convert<<<256, 256, 0, stream>>>(wq, wk, wqb, wkb);
  k_proj<<<dim3(128, 2, 2), 256, 0, stream>>>(x, wqb, wkb, qb, kb, Qb, Kb);
  k_scores<<<512, 256, 0, stream>>>(Qb, Kb, iw, out);
}